// Round 13
// baseline (254.429 us; speedup 1.0000x reference)
//
#include <hip/hip_runtime.h>
#include <hip/hip_bf16.h>

#define NEMBD 1024
#define NHEAD 16
#define HD    64
#define BB    4
#define TT    2048
#define MM    (BB*TT)      // 8192 rows
#define NQKV  (3*NEMBD)    // 3072

typedef unsigned short u16;
typedef __attribute__((ext_vector_type(8))) short short8;
typedef __attribute__((ext_vector_type(4))) float floatx4;
typedef __attribute__((ext_vector_type(16))) float floatx16;

__device__ __forceinline__ u16 f2bf(float f) {
    __hip_bfloat16 h = __float2bfloat16(f);
    return *reinterpret_cast<u16*>(&h);
}

__device__ __forceinline__ unsigned pack_bf16(float a, float b) {  // RNE
    __hip_bfloat162 h2 = __float22bfloat162_rn(float2{a, b});
    return *reinterpret_cast<unsigned*>(&h2);
}

// single-instruction truncating bf16 pack: low16 = trunc(a), high16 = trunc(b)
__device__ __forceinline__ unsigned trunc_pack(float a, float b) {
    return __builtin_amdgcn_perm(__float_as_uint(b), __float_as_uint(a), 0x07060302u);
}

// async global->LDS, 16 B per lane; LDS dest = wave-uniform base + lane*16
__device__ __forceinline__ void gl_lds16(const u16* g, u16* l) {
    __builtin_amdgcn_global_load_lds(
        (const __attribute__((address_space(1))) unsigned int*)g,
        (__attribute__((address_space(3))) unsigned int*)l,
        16, 0, 0);
}

// scale a bf16x8 fragment by c (unpack->mul->RNE repack)
__device__ __forceinline__ short8 scale8(short8 f, float c) {
    union { short8 s; unsigned u[4]; } a, r;
    a.s = f;
    for (int i = 0; i < 4; i++) {
        float lo = __uint_as_float(a.u[i] << 16) * c;
        float hi = __uint_as_float(a.u[i] & 0xffff0000u) * c;
        r.u[i] = pack_bf16(lo, hi);
    }
    return r.s;
}

// ---------------- cast fp32 -> bf16 (flat) ----------------
__global__ __launch_bounds__(256) void cast_f32_bf16(const float* __restrict__ in,
                                                     u16* __restrict__ out, int n) {
    int i = (blockIdx.x * 256 + threadIdx.x) * 4;
    if (i < n) {
        float4 v = *(const float4*)(in + i);
        uint2 o;
        o.x = pack_bf16(v.x, v.y);
        o.y = pack_bf16(v.z, v.w);
        *(uint2*)(out + i) = o;
    }
}

// ---------------- transpose + cast: in[K][N] fp32 -> out[N][K] bf16 ----------------
__global__ __launch_bounds__(256) void transpose_cast(const float* __restrict__ in,
                                                      u16* __restrict__ out, int K, int N) {
    __shared__ float tile[32][33];
    int n0 = blockIdx.x * 32, k0 = blockIdx.y * 32;
    int tx = threadIdx.x, ty = threadIdx.y;  // 32 x 8
    for (int i = 0; i < 4; i++)
        tile[ty + i * 8][tx] = in[(k0 + ty + i * 8) * N + n0 + tx];
    __syncthreads();
    for (int i = 0; i < 4; i++)
        out[(n0 + ty + i * 8) * K + k0 + tx] = f2bf(tile[tx][ty + i * 8]);
}

// ---------------- GEMM, 32x32x16 MFMA, BK=64 ----------------
// C[M][N] = A[M][K]bf16 * Bt[N][K]^T + bias.
// Staging: global_load_lds width=16 into unpadded [128][64] tiles, lane fetches
// global chunk (lane&7)^(lane>>3) so LDS[row][phys] holds logical chunk
// phys^(row&7). Fragment reads (32 rows, chunk kc*2+(lane>>5)) then alias only
// 4-way (1.58x) instead of 8-way, and there are half as many as with 16x16x32.
// T1 XCD swizzle: measured neutral (r11: 254.03 vs r5 254.16) -- gemm is not
// L2-locality-bound -- kept as free hygiene.
template <int EPI>
__global__ __launch_bounds__(256)
void gemm_bt(const u16* __restrict__ A, const u16* __restrict__ Bt,
             const float* __restrict__ bias, void* __restrict__ out0,
             u16* __restrict__ outK, u16* __restrict__ outV) {
    const int K = NEMBD;
    __shared__ u16 As[128 * 64];
    __shared__ u16 Bs[128 * 64];
    int tid = threadIdx.x;
    int lane = tid & 63, w = tid >> 6;
    int l32 = lane & 31, lhi = lane >> 5;   // row-in-tile, k-half
    int wm = w >> 1, wn = w & 1;

    // XCD-aware block swizzle (8 XCDs, round-robin dispatch -> chunked)
    int gx = gridDim.x;
    int lin = blockIdx.y * gx + blockIdx.x;
    int cpx = (gx * gridDim.y) >> 3;   // nwg/8, nwg % 8 == 0
    int swz = (lin & 7) * cpx + (lin >> 3);
    int bN = (swz % gx) * 128, bM = (swz / gx) * 128;

    floatx16 acc[2][2];
    for (int i = 0; i < 2; i++)
        for (int j = 0; j < 2; j++)
            acc[i][j] = (floatx16)(0.f);

    // staging: wave w, instr i covers rows [w*32+i*8, +8); lane -> row +(lane>>3),
    // global 16B-chunk (lane&7)^(lane>>3)
    int srow = lane >> 3;
    int scol = ((lane & 7) ^ srow) * 8;
    const u16* Ag = A  + (size_t)(bM + w * 32 + srow) * K + scol;
    const u16* Bg = Bt + (size_t)(bN + w * 32 + srow) * K + scol;

    // fragment read: row r = tile_m + l32, logical chunk kc*2+lhi -> phys ^ (lane&7)
    int physo[4];
    for (int kc = 0; kc < 4; kc++)
        physo[kc] = ((kc * 2 + lhi) ^ (lane & 7)) * 8;

    for (int k0 = 0; k0 < K; k0 += 64) {
        for (int i = 0; i < 4; i++) {
            gl_lds16(Ag + (size_t)i * 8 * K + k0, &As[(w * 32 + i * 8) * 64]);
            gl_lds16(Bg + (size_t)i * 8 * K + k0, &Bs[(w * 32 + i * 8) * 64]);
        }
        __syncthreads();
        for (int kc = 0; kc < 4; kc++) {
            short8 af[2], bf[2];
            for (int i = 0; i < 2; i++)
                af[i] = *(const short8*)&As[(wm * 64 + i * 32 + l32) * 64 + physo[kc]];
            for (int j = 0; j < 2; j++)
                bf[j] = *(const short8*)&Bs[(wn * 64 + j * 32 + l32) * 64 + physo[kc]];
            for (int i = 0; i < 2; i++)
                for (int j = 0; j < 2; j++)
                    acc[i][j] = __builtin_amdgcn_mfma_f32_32x32x16_bf16(af[i], bf[j], acc[i][j], 0, 0, 0);
        }
        __syncthreads();
    }

    // C/D layout (32x32): col = lane&31, row = (reg&3) + 8*(reg>>2) + 4*(lane>>5)
    for (int j = 0; j < 2; j++) {
        int n = bN + wn * 64 + j * 32 + l32;
        float bv = bias[n];
        for (int i = 0; i < 2; i++) {
            int mbase = bM + wm * 64 + i * 32 + 4 * lhi;
            for (int reg = 0; reg < 16; reg++) {
                float v = acc[i][j][reg] + bv;
                int mg = mbase + (reg & 3) + 8 * (reg >> 2);
                if (EPI == 0) {
                    int which = n >> 10, c = n & 1023;
                    int h = c >> 6, d = c & 63;
                    int b = mg >> 11, t = mg & 2047;
                    u16* dst = (which == 0) ? (u16*)out0 : (which == 1 ? outK : outV);
                    dst[(((size_t)(b * NHEAD + h) * TT) + t) * HD + d] = f2bf(v);
                } else {
                    ((float*)out0)[(size_t)mg * NEMBD + n] = v;
                }
            }
        }
    }
}

// ---------------- transposed flash attention: one 128-row q-tile per block,
// fixed-base softmax, DOUBLE-buffered K/V LDS + register prefetch (1 barrier per
// k-step -- stage_write of tile k+1 overlaps nothing-waiting; the r0 kernel
// proved this exact staging pattern correct).  Compute structure = round-5
// measured-best (86.4-87.0 x3); + r12 balance map (74.7).
// LDS 55296 B -> 2 blocks/CU, which matches the ~22% measured occupancy of the
// 36864-B version anyway (capacity wasn't the binding constraint).
// VGPR must stay <= 128: launch_bounds(256,2) -- (256,4) squeezed arch-VGPRs
// to 64 and spilled ~110 MB scratch (r3, 2x regr).
// WORK BALANCE (r12, +11.7 us): work per block ~ (jq+1); co-resident blocks
// have blockIdx.y differing by 4k.  y -> jq via f = [b, 7-b, 15-b, 8+b][y>>2]
// (b = y&3): bijective; pairs (dy=8) sum to 17 work units, quadruples (dy=4)
// sum to 34 -- both co-residency granularities exactly balanced.
__global__ __launch_bounds__(256, 2)
void attn_kernel(const u16* __restrict__ Q, const u16* __restrict__ Kg,
                 const u16* __restrict__ V, u16* __restrict__ Y) {
    __shared__ u16 Ks[2][64][72];
    __shared__ u16 Vt[2][64][72];
    __shared__ u16 Ps[4][32][72];

    int tid = threadIdx.x;
    int lane = tid & 63, w = tid >> 6;
    int quad = lane >> 4, l16 = lane & 15;
    int bh = blockIdx.x;                 // 0..63
    int yb = blockIdx.y & 3, ya = blockIdx.y >> 2;
    int jq = (ya == 0) ? yb : (ya == 1) ? 7 - yb : (ya == 2) ? 15 - yb : 8 + yb;
    int q0 = jq * 128;
    const u16* Qb = Q  + (size_t)bh * TT * HD;
    const u16* Kb = Kg + (size_t)bh * TT * HD;
    const u16* Vb = V  + (size_t)bh * TT * HD;
    int wq = q0 + w * 32;

    const float C = 0.18033688f;  // (1/sqrt(64)) * log2(e), folded into Q

    short8 qf[2][2];
    for (int qt = 0; qt < 2; qt++)
        for (int kd = 0; kd < 2; kd++)
            qf[qt][kd] = scale8(*(const short8*)(Qb + (size_t)(wq + qt * 16 + l16) * HD + kd * 32 + quad * 8), C);

    floatx4 o[4][2];
    for (int dt = 0; dt < 4; dt++)
        for (int qt = 0; qt < 2; qt++)
            o[dt][qt] = (floatx4){0.f, 0.f, 0.f, 0.f};
    float l_s[2] = {0.f, 0.f};

    int krow = tid >> 2, kcg = (tid & 3) * 16;
    int vkp = (tid & 31) * 2, vd0 = (tid >> 5) * 8;

    auto stage_write = [&](int bp, uint4 k0v, uint4 k1v, uint4 v0, uint4 v1) {
        *(uint4*)&Ks[bp][krow][kcg]     = k0v;
        *(uint4*)&Ks[bp][krow][kcg + 8] = k1v;
        const unsigned* w0p = (const unsigned*)&v0;
        const unsigned* w1p = (const unsigned*)&v1;
        for (int e = 0; e < 4; e++) {
            *(unsigned*)&Vt[bp][vd0 + 2 * e][vkp]     = __builtin_amdgcn_perm(w1p[e], w0p[e], 0x05040100u);
            *(unsigned*)&Vt[bp][vd0 + 2 * e + 1][vkp] = __builtin_amdgcn_perm(w1p[e], w0p[e], 0x07060302u);
        }
    };

    auto process = [&](int k0, int bp) {
        short8 kf[4][2];
        for (int kt = 0; kt < 4; kt++)
            for (int kd = 0; kd < 2; kd++)
                kf[kt][kd] = *(const short8*)&Ks[bp][kt * 16 + l16][kd * 32 + quad * 8];

        floatx4 s[2][4];
        for (int qt = 0; qt < 2; qt++)
            for (int kt = 0; kt < 4; kt++) {
                floatx4 a = (floatx4){0.f, 0.f, 0.f, 0.f};
                a = __builtin_amdgcn_mfma_f32_16x16x32_bf16(kf[kt][0], qf[qt][0], a, 0, 0, 0);
                a = __builtin_amdgcn_mfma_f32_16x16x32_bf16(kf[kt][1], qf[qt][1], a, 0, 0, 0);
                s[qt][kt] = a;
            }

        bool diag = (k0 + 64 > wq);
        for (int qt = 0; qt < 2; qt++) {
            int qg = wq + qt * 16 + l16;
            if (diag) {
                for (int kt = 0; kt < 4; kt++)
                    for (int r = 0; r < 4; r++)
                        if (k0 + kt * 16 + quad * 4 + r > qg) s[qt][kt][r] = -INFINITY;
            }
            float rs = 0.f;
            for (int kt = 0; kt < 4; kt++)
                for (int r = 0; r < 4; r++) {
                    float p = exp2f(s[qt][kt][r]);
                    s[qt][kt][r] = p;
                    rs += p;
                }
            l_s[qt] += rs;
        }

        for (int qt = 0; qt < 2; qt++)
            for (int kt = 0; kt < 4; kt++) {
                floatx4 p = s[qt][kt];
                *(unsigned*)&Ps[w][qt * 16 + l16][kt * 16 + quad * 4]     = trunc_pack(p[0], p[1]);
                *(unsigned*)&Ps[w][qt * 16 + l16][kt * 16 + quad * 4 + 2] = trunc_pack(p[2], p[3]);
            }
        short8 pfrag[2][2];
        for (int qt = 0; qt < 2; qt++)
            for (int c = 0; c < 2; c++)
                pfrag[qt][c] = *(const short8*)&Ps[w][qt * 16 + l16][c * 32 + quad * 8];
        for (int c = 0; c < 2; c++)
            for (int dt = 0; dt < 4; dt++) {
                short8 vfrag = *(const short8*)&Vt[bp][dt * 16 + l16][c * 32 + quad * 8];
                for (int qt = 0; qt < 2; qt++)
                    o[dt][qt] = __builtin_amdgcn_mfma_f32_16x16x32_bf16(vfrag, pfrag[qt][c], o[dt][qt], 0, 0, 0);
            }
    };

    // ---- prologue: stage step 0 into buf 0 ----
    {
        uint4 k0v = *(const uint4*)(Kb + (size_t)krow * HD + kcg);
        uint4 k1v = *(const uint4*)(Kb + (size_t)krow * HD + kcg + 8);
        uint4 v0  = *(const uint4*)(Vb + (size_t)vkp * HD + vd0);
        uint4 v1  = *(const uint4*)(Vb + (size_t)(vkp + 1) * HD + vd0);
        stage_write(0, k0v, k1v, v0, v1);
    }
    __syncthreads();

    int kend = q0 + 128;
    int p = 0;
    for (int k0 = 0; k0 < kend; k0 += 64, p ^= 1) {
        bool pref = (k0 + 64 < kend);
        uint4 nk0, nk1, nv0, nv1;
        if (pref) {
            nk0 = *(const uint4*)(Kb + (size_t)(k0 + 64 + krow) * HD + kcg);
            nk1 = *(const uint4*)(Kb + (size_t)(k0 + 64 + krow) * HD + kcg + 8);
            nv0 = *(const uint4*)(Vb + (size_t)(k0 + 64 + vkp) * HD + vd0);
            nv1 = *(const uint4*)(Vb + (size_t)(k0 + 64 + vkp + 1) * HD + vd0);
        }

        if (k0 < wq + 32) process(k0, p);

        if (pref) stage_write(p ^ 1, nk0, nk1, nv0, nv1);
        __syncthreads();
    }

    // ---- epilogue: reduce l across quads, O^T[d][q] -> Y[b, q, h*64+d] ----
    int b = bh >> 4, h = bh & 15;
    for (int qt = 0; qt < 2; qt++) {
        float lt = l_s[qt];
        lt += __shfl_xor(lt, 16, 64);
        lt += __shfl_xor(lt, 32, 64);
        float inv = 1.0f / lt;
        int qg = wq + qt * 16 + l16;
        size_t base = ((size_t)(b * TT + qg)) * NEMBD + h * HD;
        for (int dt = 0; dt < 4; dt++) {
            *(unsigned*)&Y[base + dt * 16 + quad * 4]     = pack_bf16(o[dt][qt][0] * inv, o[dt][qt][1] * inv);
            *(unsigned*)&Y[base + dt * 16 + quad * 4 + 2] = pack_bf16(o[dt][qt][2] * inv, o[dt][qt][3] * inv);
        }
    }
}

extern "C" void kernel_launch(void* const* d_in, const int* in_sizes, int n_in,
                              void* d_out, int out_size, void* d_ws, size_t ws_size,
                              hipStream_t stream) {
    const float* x      = (const float*)d_in[0];
    const float* W_attn = (const float*)d_in[1];
    const float* b_attn = (const float*)d_in[2];
    const float* W_proj = (const float*)d_in[3];
    const float* b_proj = (const float*)d_in[4];
    float* out = (float*)d_out;

    char* ws = (char*)d_ws;
    u16* xb  = (u16*)(ws + 0);          // 16 MiB (reused as Y after QKV GEMM)
    u16* wat = (u16*)(ws + 16777216);   //  6 MiB
    u16* wpt = (u16*)(ws + 23068672);   //  2 MiB
    u16* Qb  = (u16*)(ws + 25165824);   // 16 MiB
    u16* Kb  = (u16*)(ws + 41943040);   // 16 MiB
    u16* Vb  = (u16*)(ws + 58720256);   // 16 MiB (end 75,497,472)

    cast_f32_bf16<<<(MM * NEMBD / 4 + 255) / 256, 256, 0, stream>>>(x, xb, MM * NEMBD);
    dim3 tb(32, 8);
    transpose_cast<<<dim3(NQKV / 32, NEMBD / 32), tb, 0, stream>>>(W_attn, wat, NEMBD, NQKV);
    transpose_cast<<<dim3(NEMBD / 32, NEMBD / 32), tb, 0, stream>>>(W_proj, wpt, NEMBD, NEMBD);

    gemm_bt<0><<<dim3(NQKV / 128, MM / 128), 256, 0, stream>>>(xb, wat, b_attn, (void*)Qb, Kb, Vb);
    attn_kernel<<<dim3(BB * NHEAD, 16), 256, 0, stream>>>(Qb, Kb, Vb, xb);
    gemm_bt<1><<<dim3(NEMBD / 128, MM / 128), 256, 0, stream>>>(xb, wpt, b_proj, (void*)out, nullptr, nullptr);
}

// Round 14
// 240.900 us; speedup vs baseline: 1.0562x; 1.0562x over previous
//
#include <hip/hip_runtime.h>
#include <hip/hip_bf16.h>

#define NEMBD 1024
#define NHEAD 16
#define HD    64
#define BB    4
#define TT    2048
#define MM    (BB*TT)      // 8192 rows
#define NQKV  (3*NEMBD)    // 3072

typedef unsigned short u16;
typedef __attribute__((ext_vector_type(8))) short short8;
typedef __attribute__((ext_vector_type(4))) float floatx4;
typedef __attribute__((ext_vector_type(16))) float floatx16;

__device__ __forceinline__ u16 f2bf(float f) {
    __hip_bfloat16 h = __float2bfloat16(f);
    return *reinterpret_cast<u16*>(&h);
}

__device__ __forceinline__ unsigned pack_bf16(float a, float b) {  // RNE
    __hip_bfloat162 h2 = __float22bfloat162_rn(float2{a, b});
    return *reinterpret_cast<unsigned*>(&h2);
}

// single-instruction truncating bf16 pack: low16 = trunc(a), high16 = trunc(b)
__device__ __forceinline__ unsigned trunc_pack(float a, float b) {
    return __builtin_amdgcn_perm(__float_as_uint(b), __float_as_uint(a), 0x07060302u);
}

// async global->LDS, 16 B per lane; LDS dest = wave-uniform base + lane*16
__device__ __forceinline__ void gl_lds16(const u16* g, u16* l) {
    __builtin_amdgcn_global_load_lds(
        (const __attribute__((address_space(1))) unsigned int*)g,
        (__attribute__((address_space(3))) unsigned int*)l,
        16, 0, 0);
}

// scale a bf16x8 fragment by c (unpack->mul->RNE repack)
__device__ __forceinline__ short8 scale8(short8 f, float c) {
    union { short8 s; unsigned u[4]; } a, r;
    a.s = f;
    for (int i = 0; i < 4; i++) {
        float lo = __uint_as_float(a.u[i] << 16) * c;
        float hi = __uint_as_float(a.u[i] & 0xffff0000u) * c;
        r.u[i] = pack_bf16(lo, hi);
    }
    return r.s;
}

// ---------------- cast fp32 -> bf16 (flat) ----------------
__global__ __launch_bounds__(256) void cast_f32_bf16(const float* __restrict__ in,
                                                     u16* __restrict__ out, int n) {
    int i = (blockIdx.x * 256 + threadIdx.x) * 4;
    if (i < n) {
        float4 v = *(const float4*)(in + i);
        uint2 o;
        o.x = pack_bf16(v.x, v.y);
        o.y = pack_bf16(v.z, v.w);
        *(uint2*)(out + i) = o;
    }
}

// ---------------- transpose + cast: in[K][N] fp32 -> out[N][K] bf16 ----------------
__global__ __launch_bounds__(256) void transpose_cast(const float* __restrict__ in,
                                                      u16* __restrict__ out, int K, int N) {
    __shared__ float tile[32][33];
    int n0 = blockIdx.x * 32, k0 = blockIdx.y * 32;
    int tx = threadIdx.x, ty = threadIdx.y;  // 32 x 8
    for (int i = 0; i < 4; i++)
        tile[ty + i * 8][tx] = in[(k0 + ty + i * 8) * N + n0 + tx];
    __syncthreads();
    for (int i = 0; i < 4; i++)
        out[(n0 + ty + i * 8) * K + k0 + tx] = f2bf(tile[tx][ty + i * 8]);
}

// ---------------- GEMM, 32x32x16 MFMA, BK=64 ----------------
// C[M][N] = A[M][K]bf16 * Bt[N][K]^T + bias.
// Staging: global_load_lds width=16 into unpadded [128][64] tiles, lane fetches
// global chunk (lane&7)^(lane>>3) so LDS[row][phys] holds logical chunk
// phys^(row&7). Fragment reads (32 rows, chunk kc*2+(lane>>5)) then alias only
// 4-way (1.58x) instead of 8-way, and there are half as many as with 16x16x32.
// T1 XCD swizzle: measured neutral (r11) -- kept as free hygiene.
template <int EPI>
__global__ __launch_bounds__(256)
void gemm_bt(const u16* __restrict__ A, const u16* __restrict__ Bt,
             const float* __restrict__ bias, void* __restrict__ out0,
             u16* __restrict__ outK, u16* __restrict__ outV) {
    const int K = NEMBD;
    __shared__ u16 As[128 * 64];
    __shared__ u16 Bs[128 * 64];
    int tid = threadIdx.x;
    int lane = tid & 63, w = tid >> 6;
    int l32 = lane & 31, lhi = lane >> 5;   // row-in-tile, k-half
    int wm = w >> 1, wn = w & 1;

    // XCD-aware block swizzle (8 XCDs, round-robin dispatch -> chunked)
    int gx = gridDim.x;
    int lin = blockIdx.y * gx + blockIdx.x;
    int cpx = (gx * gridDim.y) >> 3;   // nwg/8, nwg % 8 == 0
    int swz = (lin & 7) * cpx + (lin >> 3);
    int bN = (swz % gx) * 128, bM = (swz / gx) * 128;

    floatx16 acc[2][2];
    for (int i = 0; i < 2; i++)
        for (int j = 0; j < 2; j++)
            acc[i][j] = (floatx16)(0.f);

    // staging: wave w, instr i covers rows [w*32+i*8, +8); lane -> row +(lane>>3),
    // global 16B-chunk (lane&7)^(lane>>3)
    int srow = lane >> 3;
    int scol = ((lane & 7) ^ srow) * 8;
    const u16* Ag = A  + (size_t)(bM + w * 32 + srow) * K + scol;
    const u16* Bg = Bt + (size_t)(bN + w * 32 + srow) * K + scol;

    // fragment read: row r = tile_m + l32, logical chunk kc*2+lhi -> phys ^ (lane&7)
    int physo[4];
    for (int kc = 0; kc < 4; kc++)
        physo[kc] = ((kc * 2 + lhi) ^ (lane & 7)) * 8;

    for (int k0 = 0; k0 < K; k0 += 64) {
        for (int i = 0; i < 4; i++) {
            gl_lds16(Ag + (size_t)i * 8 * K + k0, &As[(w * 32 + i * 8) * 64]);
            gl_lds16(Bg + (size_t)i * 8 * K + k0, &Bs[(w * 32 + i * 8) * 64]);
        }
        __syncthreads();
        for (int kc = 0; kc < 4; kc++) {
            short8 af[2], bf[2];
            for (int i = 0; i < 2; i++)
                af[i] = *(const short8*)&As[(wm * 64 + i * 32 + l32) * 64 + physo[kc]];
            for (int j = 0; j < 2; j++)
                bf[j] = *(const short8*)&Bs[(wn * 64 + j * 32 + l32) * 64 + physo[kc]];
            for (int i = 0; i < 2; i++)
                for (int j = 0; j < 2; j++)
                    acc[i][j] = __builtin_amdgcn_mfma_f32_32x32x16_bf16(af[i], bf[j], acc[i][j], 0, 0, 0);
        }
        __syncthreads();
    }

    // C/D layout (32x32): col = lane&31, row = (reg&3) + 8*(reg>>2) + 4*(lane>>5)
    for (int j = 0; j < 2; j++) {
        int n = bN + wn * 64 + j * 32 + l32;
        float bv = bias[n];
        for (int i = 0; i < 2; i++) {
            int mbase = bM + wm * 64 + i * 32 + 4 * lhi;
            for (int reg = 0; reg < 16; reg++) {
                float v = acc[i][j][reg] + bv;
                int mg = mbase + (reg & 3) + 8 * (reg >> 2);
                if (EPI == 0) {
                    int which = n >> 10, c = n & 1023;
                    int h = c >> 6, d = c & 63;
                    int b = mg >> 11, t = mg & 2047;
                    u16* dst = (which == 0) ? (u16*)out0 : (which == 1 ? outK : outV);
                    dst[(((size_t)(b * NHEAD + h) * TT) + t) * HD + d] = f2bf(v);
                } else {
                    ((float*)out0)[(size_t)mg * NEMBD + n] = v;
                }
            }
        }
    }
}

// ---------------- transposed flash attention: one 128-row q-tile per block,
// fixed-base softmax, single-buffered K/V LDS + register prefetch.
// REVERT to r12 structure (74.7 us, session best).  r13's K/V double-buffer
// (LDS 55296) cut block capacity 4->2/CU, occupancy 22.4->17.6%, dur 74.7->80.0
// -- capacity WAS binding; cross-block wave overlap is what hides the barriers.
// r14 refinement: Ps writes fused b32x2 -> b64 (uint2, 8B-aligned) -- the Ps
// write pattern hits only even banks (4-way conflict, 7.57M conflict cycles
// ~12us/CU); halving the instruction count halves that serialization.
// 1024 blocks, LDS 36864 B.  VGPR must stay <= 128: launch_bounds(256,2) --
// (256,4) squeezed arch-VGPRs to 64 and spilled ~110 MB scratch (r3, 2x regr).
// WORK BALANCE (r12, +11.7 us): work per block ~ (jq+1); co-resident blocks
// have blockIdx.y differing by 4k.  y -> jq via f = [b, 7-b, 15-b, 8+b][y>>2]
// (b = y&3): bijective; pairs (dy=8) sum to 17 work units, quadruples (dy=4)
// sum to 34 -- both co-residency granularities exactly balanced.
__global__ __launch_bounds__(256, 2)
void attn_kernel(const u16* __restrict__ Q, const u16* __restrict__ Kg,
                 const u16* __restrict__ V, u16* __restrict__ Y) {
    __shared__ u16 Ks[64][72];
    __shared__ u16 Vt[64][72];
    __shared__ u16 Ps[4][32][72];

    int tid = threadIdx.x;
    int lane = tid & 63, w = tid >> 6;
    int quad = lane >> 4, l16 = lane & 15;
    int bh = blockIdx.x;                 // 0..63
    int yb = blockIdx.y & 3, ya = blockIdx.y >> 2;
    int jq = (ya == 0) ? yb : (ya == 1) ? 7 - yb : (ya == 2) ? 15 - yb : 8 + yb;
    int q0 = jq * 128;
    const u16* Qb = Q  + (size_t)bh * TT * HD;
    const u16* Kb = Kg + (size_t)bh * TT * HD;
    const u16* Vb = V  + (size_t)bh * TT * HD;
    int wq = q0 + w * 32;

    const float C = 0.18033688f;  // (1/sqrt(64)) * log2(e), folded into Q

    short8 qf[2][2];
    for (int qt = 0; qt < 2; qt++)
        for (int kd = 0; kd < 2; kd++)
            qf[qt][kd] = scale8(*(const short8*)(Qb + (size_t)(wq + qt * 16 + l16) * HD + kd * 32 + quad * 8), C);

    floatx4 o[4][2];
    for (int dt = 0; dt < 4; dt++)
        for (int qt = 0; qt < 2; qt++)
            o[dt][qt] = (floatx4){0.f, 0.f, 0.f, 0.f};
    float l_s[2] = {0.f, 0.f};

    int krow = tid >> 2, kcg = (tid & 3) * 16;
    int vkp = (tid & 31) * 2, vd0 = (tid >> 5) * 8;

    auto stage_write = [&](uint4 k0v, uint4 k1v, uint4 v0, uint4 v1) {
        *(uint4*)&Ks[krow][kcg]     = k0v;
        *(uint4*)&Ks[krow][kcg + 8] = k1v;
        const unsigned* w0p = (const unsigned*)&v0;
        const unsigned* w1p = (const unsigned*)&v1;
        for (int e = 0; e < 4; e++) {
            *(unsigned*)&Vt[vd0 + 2 * e][vkp]     = __builtin_amdgcn_perm(w1p[e], w0p[e], 0x05040100u);
            *(unsigned*)&Vt[vd0 + 2 * e + 1][vkp] = __builtin_amdgcn_perm(w1p[e], w0p[e], 0x07060302u);
        }
    };

    auto process = [&](int k0) {
        short8 kf[4][2];
        for (int kt = 0; kt < 4; kt++)
            for (int kd = 0; kd < 2; kd++)
                kf[kt][kd] = *(const short8*)&Ks[kt * 16 + l16][kd * 32 + quad * 8];

        floatx4 s[2][4];
        for (int qt = 0; qt < 2; qt++)
            for (int kt = 0; kt < 4; kt++) {
                floatx4 a = (floatx4){0.f, 0.f, 0.f, 0.f};
                a = __builtin_amdgcn_mfma_f32_16x16x32_bf16(kf[kt][0], qf[qt][0], a, 0, 0, 0);
                a = __builtin_amdgcn_mfma_f32_16x16x32_bf16(kf[kt][1], qf[qt][1], a, 0, 0, 0);
                s[qt][kt] = a;
            }

        bool diag = (k0 + 64 > wq);
        for (int qt = 0; qt < 2; qt++) {
            int qg = wq + qt * 16 + l16;
            if (diag) {
                for (int kt = 0; kt < 4; kt++)
                    for (int r = 0; r < 4; r++)
                        if (k0 + kt * 16 + quad * 4 + r > qg) s[qt][kt][r] = -INFINITY;
            }
            float rs = 0.f;
            for (int kt = 0; kt < 4; kt++)
                for (int r = 0; r < 4; r++) {
                    float p = exp2f(s[qt][kt][r]);
                    s[qt][kt][r] = p;
                    rs += p;
                }
            l_s[qt] += rs;
        }

        for (int qt = 0; qt < 2; qt++)
            for (int kt = 0; kt < 4; kt++) {
                floatx4 p = s[qt][kt];
                uint2 pw;
                pw.x = trunc_pack(p[0], p[1]);
                pw.y = trunc_pack(p[2], p[3]);
                *(uint2*)&Ps[w][qt * 16 + l16][kt * 16 + quad * 4] = pw;
            }
        short8 pfrag[2][2];
        for (int qt = 0; qt < 2; qt++)
            for (int c = 0; c < 2; c++)
                pfrag[qt][c] = *(const short8*)&Ps[w][qt * 16 + l16][c * 32 + quad * 8];
        for (int c = 0; c < 2; c++)
            for (int dt = 0; dt < 4; dt++) {
                short8 vfrag = *(const short8*)&Vt[dt * 16 + l16][c * 32 + quad * 8];
                for (int qt = 0; qt < 2; qt++)
                    o[dt][qt] = __builtin_amdgcn_mfma_f32_16x16x32_bf16(vfrag, pfrag[qt][c], o[dt][qt], 0, 0, 0);
            }
    };

    // ---- prologue: stage step 0 ----
    {
        uint4 k0v = *(const uint4*)(Kb + (size_t)krow * HD + kcg);
        uint4 k1v = *(const uint4*)(Kb + (size_t)krow * HD + kcg + 8);
        uint4 v0  = *(const uint4*)(Vb + (size_t)vkp * HD + vd0);
        uint4 v1  = *(const uint4*)(Vb + (size_t)(vkp + 1) * HD + vd0);
        stage_write(k0v, k1v, v0, v1);
    }
    __syncthreads();

    int kend = q0 + 128;
    for (int k0 = 0; k0 < kend; k0 += 64) {
        bool pref = (k0 + 64 < kend);
        uint4 nk0, nk1, nv0, nv1;
        if (pref) {
            nk0 = *(const uint4*)(Kb + (size_t)(k0 + 64 + krow) * HD + kcg);
            nk1 = *(const uint4*)(Kb + (size_t)(k0 + 64 + krow) * HD + kcg + 8);
            nv0 = *(const uint4*)(Vb + (size_t)(k0 + 64 + vkp) * HD + vd0);
            nv1 = *(const uint4*)(Vb + (size_t)(k0 + 64 + vkp + 1) * HD + vd0);
        }

        if (k0 < wq + 32) process(k0);

        __syncthreads();
        if (pref) {
            stage_write(nk0, nk1, nv0, nv1);
        }
        __syncthreads();
    }

    // ---- epilogue: reduce l across quads, O^T[d][q] -> Y[b, q, h*64+d] ----
    int b = bh >> 4, h = bh & 15;
    for (int qt = 0; qt < 2; qt++) {
        float lt = l_s[qt];
        lt += __shfl_xor(lt, 16, 64);
        lt += __shfl_xor(lt, 32, 64);
        float inv = 1.0f / lt;
        int qg = wq + qt * 16 + l16;
        size_t base = ((size_t)(b * TT + qg)) * NEMBD + h * HD;
        for (int dt = 0; dt < 4; dt++) {
            *(unsigned*)&Y[base + dt * 16 + quad * 4]     = pack_bf16(o[dt][qt][0] * inv, o[dt][qt][1] * inv);
            *(unsigned*)&Y[base + dt * 16 + quad * 4 + 2] = pack_bf16(o[dt][qt][2] * inv, o[dt][qt][3] * inv);
        }
    }
}

extern "C" void kernel_launch(void* const* d_in, const int* in_sizes, int n_in,
                              void* d_out, int out_size, void* d_ws, size_t ws_size,
                              hipStream_t stream) {
    const float* x      = (const float*)d_in[0];
    const float* W_attn = (const float*)d_in[1];
    const float* b_attn = (const float*)d_in[2];
    const float* W_proj = (const float*)d_in[3];
    const float* b_proj = (const float*)d_in[4];
    float* out = (float*)d_out;

    char* ws = (char*)d_ws;
    u16* xb  = (u16*)(ws + 0);          // 16 MiB (reused as Y after QKV GEMM)
    u16* wat = (u16*)(ws + 16777216);   //  6 MiB
    u16* wpt = (u16*)(ws + 23068672);   //  2 MiB
    u16* Qb  = (u16*)(ws + 25165824);   // 16 MiB
    u16* Kb  = (u16*)(ws + 41943040);   // 16 MiB
    u16* Vb  = (u16*)(ws + 58720256);   // 16 MiB (end 75,497,472)

    cast_f32_bf16<<<(MM * NEMBD / 4 + 255) / 256, 256, 0, stream>>>(x, xb, MM * NEMBD);
    dim3 tb(32, 8);
    transpose_cast<<<dim3(NQKV / 32, NEMBD / 32), tb, 0, stream>>>(W_attn, wat, NEMBD, NQKV);
    transpose_cast<<<dim3(NEMBD / 32, NEMBD / 32), tb, 0, stream>>>(W_proj, wpt, NEMBD, NEMBD);

    gemm_bt<0><<<dim3(NQKV / 128, MM / 128), 256, 0, stream>>>(xb, wat, b_attn, (void*)Qb, Kb, Vb);
    attn_kernel<<<dim3(BB * NHEAD, 16), 256, 0, stream>>>(Qb, Kb, Vb, xb);
    gemm_bt<1><<<dim3(NEMBD / 128, MM / 128), 256, 0, stream>>>(xb, wpt, b_proj, (void*)out, nullptr, nullptr);
}

// Round 16
// 240.384 us; speedup vs baseline: 1.0584x; 1.0021x over previous
//
#include <hip/hip_runtime.h>
#include <hip/hip_bf16.h>

#define NEMBD 1024
#define NHEAD 16
#define HD    64
#define BB    4
#define TT    2048
#define MM    (BB*TT)      // 8192 rows
#define NQKV  (3*NEMBD)    // 3072

typedef unsigned short u16;
typedef __attribute__((ext_vector_type(8))) short short8;
typedef __attribute__((ext_vector_type(4))) float floatx4;
typedef __attribute__((ext_vector_type(16))) float floatx16;

__device__ __forceinline__ u16 f2bf(float f) {
    __hip_bfloat16 h = __float2bfloat16(f);
    return *reinterpret_cast<u16*>(&h);
}

__device__ __forceinline__ unsigned pack_bf16(float a, float b) {  // RNE
    __hip_bfloat162 h2 = __float22bfloat162_rn(float2{a, b});
    return *reinterpret_cast<unsigned*>(&h2);
}

// single-instruction truncating bf16 pack: low16 = trunc(a), high16 = trunc(b)
__device__ __forceinline__ unsigned trunc_pack(float a, float b) {
    return __builtin_amdgcn_perm(__float_as_uint(b), __float_as_uint(a), 0x07060302u);
}

// async global->LDS, 16 B per lane; LDS dest = wave-uniform base + lane*16
__device__ __forceinline__ void gl_lds16(const u16* g, u16* l) {
    __builtin_amdgcn_global_load_lds(
        (const __attribute__((address_space(1))) unsigned int*)g,
        (__attribute__((address_space(3))) unsigned int*)l,
        16, 0, 0);
}

// scale a bf16x8 fragment by c (unpack->mul->RNE repack)
__device__ __forceinline__ short8 scale8(short8 f, float c) {
    union { short8 s; unsigned u[4]; } a, r;
    a.s = f;
    for (int i = 0; i < 4; i++) {
        float lo = __uint_as_float(a.u[i] << 16) * c;
        float hi = __uint_as_float(a.u[i] & 0xffff0000u) * c;
        r.u[i] = pack_bf16(lo, hi);
    }
    return r.s;
}

// ---------------- fused prep: cast x->bf16 + transpose-cast both weights ------
// One launch instead of three: removes 2 inter-dispatch gaps and lets the three
// independent prep stages pack the GPU concurrently (cast's 8192-block tail no
// longer runs alone).  Block-range demux:
//   [0, 8192)        cast x (fp32 -> bf16, 1024 elems/block)
//   [8192, 11264)    W_attn [1024][3072] -> wat [3072][1024] bf16
//   [11264, 12288)   W_proj [1024][1024] -> wpt [1024][1024] bf16
__global__ __launch_bounds__(256)
void prep_fused(const float* __restrict__ x, u16* __restrict__ xb,
                const float* __restrict__ Wa, u16* __restrict__ wat,
                const float* __restrict__ Wp, u16* __restrict__ wpt) {
    int bid = blockIdx.x;
    int tid = threadIdx.x;
    if (bid < 8192) {                    // cast path (exact: 8192*256*4 = MM*NEMBD)
        int i = (bid * 256 + tid) * 4;
        float4 v = *(const float4*)(x + i);
        uint2 o;
        o.x = pack_bf16(v.x, v.y);
        o.y = pack_bf16(v.z, v.w);
        *(uint2*)(xb + i) = o;
    } else {                             // transpose-cast path (32x32 tile, 256 thr)
        __shared__ float tile[32][33];
        const float* in; u16* out; int N, n0, k0;
        if (bid < 8192 + 3072) {
            int b = bid - 8192;
            in = Wa; out = wat; N = NQKV;
            n0 = (b % 96) * 32; k0 = (b / 96) * 32;
        } else {
            int b = bid - 11264;
            in = Wp; out = wpt; N = NEMBD;
            n0 = (b & 31) * 32; k0 = (b >> 5) * 32;
        }
        int tx = tid & 31, ty = tid >> 5;  // 32 x 8
        for (int i = 0; i < 4; i++)
            tile[ty + i * 8][tx] = in[(size_t)(k0 + ty + i * 8) * N + n0 + tx];
        __syncthreads();
        for (int i = 0; i < 4; i++)
            out[(size_t)(n0 + ty + i * 8) * NEMBD + k0 + tx] = f2bf(tile[tx][ty + i * 8]);
    }
}

// ---------------- GEMM, 32x32x16 MFMA, BK=64 ----------------
// C[M][N] = A[M][K]bf16 * Bt[N][K]^T + bias.
// Staging: global_load_lds width=16 into unpadded [128][64] tiles, lane fetches
// global chunk (lane&7)^(lane>>3) so LDS[row][phys] holds logical chunk
// phys^(row&7). Fragment reads (32 rows, chunk kc*2+(lane>>5)) then alias only
// 4-way (1.58x) instead of 8-way, and there are half as many as with 16x16x32.
// T1 XCD swizzle: measured neutral (r11) -- kept as free hygiene.
// 2-barrier 128^2 structure is at its known ceiling (~900 TF class); the 8-phase
// 256^2 template is the only documented path past it but its vmcnt/buffer
// schedule could not be reconstructed race-free from the spec alone -- not
// shipped blind (m152 discipline).
template <int EPI>
__global__ __launch_bounds__(256)
void gemm_bt(const u16* __restrict__ A, const u16* __restrict__ Bt,
             const float* __restrict__ bias, void* __restrict__ out0,
             u16* __restrict__ outK, u16* __restrict__ outV) {
    const int K = NEMBD;
    __shared__ u16 As[128 * 64];
    __shared__ u16 Bs[128 * 64];
    int tid = threadIdx.x;
    int lane = tid & 63, w = tid >> 6;
    int l32 = lane & 31, lhi = lane >> 5;   // row-in-tile, k-half
    int wm = w >> 1, wn = w & 1;

    // XCD-aware block swizzle (8 XCDs, round-robin dispatch -> chunked)
    int gx = gridDim.x;
    int lin = blockIdx.y * gx + blockIdx.x;
    int cpx = (gx * gridDim.y) >> 3;   // nwg/8, nwg % 8 == 0
    int swz = (lin & 7) * cpx + (lin >> 3);
    int bN = (swz % gx) * 128, bM = (swz / gx) * 128;

    floatx16 acc[2][2];
    for (int i = 0; i < 2; i++)
        for (int j = 0; j < 2; j++)
            acc[i][j] = (floatx16)(0.f);

    // staging: wave w, instr i covers rows [w*32+i*8, +8); lane -> row +(lane>>3),
    // global 16B-chunk (lane&7)^(lane>>3)
    int srow = lane >> 3;
    int scol = ((lane & 7) ^ srow) * 8;
    const u16* Ag = A  + (size_t)(bM + w * 32 + srow) * K + scol;
    const u16* Bg = Bt + (size_t)(bN + w * 32 + srow) * K + scol;

    // fragment read: row r = tile_m + l32, logical chunk kc*2+lhi -> phys ^ (lane&7)
    int physo[4];
    for (int kc = 0; kc < 4; kc++)
        physo[kc] = ((kc * 2 + lhi) ^ (lane & 7)) * 8;

    for (int k0 = 0; k0 < K; k0 += 64) {
        for (int i = 0; i < 4; i++) {
            gl_lds16(Ag + (size_t)i * 8 * K + k0, &As[(w * 32 + i * 8) * 64]);
            gl_lds16(Bg + (size_t)i * 8 * K + k0, &Bs[(w * 32 + i * 8) * 64]);
        }
        __syncthreads();
        for (int kc = 0; kc < 4; kc++) {
            short8 af[2], bf[2];
            for (int i = 0; i < 2; i++)
                af[i] = *(const short8*)&As[(wm * 64 + i * 32 + l32) * 64 + physo[kc]];
            for (int j = 0; j < 2; j++)
                bf[j] = *(const short8*)&Bs[(wn * 64 + j * 32 + l32) * 64 + physo[kc]];
            for (int i = 0; i < 2; i++)
                for (int j = 0; j < 2; j++)
                    acc[i][j] = __builtin_amdgcn_mfma_f32_32x32x16_bf16(af[i], bf[j], acc[i][j], 0, 0, 0);
        }
        __syncthreads();
    }

    // C/D layout (32x32): col = lane&31, row = (reg&3) + 8*(reg>>2) + 4*(lane>>5)
    for (int j = 0; j < 2; j++) {
        int n = bN + wn * 64 + j * 32 + l32;
        float bv = bias[n];
        for (int i = 0; i < 2; i++) {
            int mbase = bM + wm * 64 + i * 32 + 4 * lhi;
            for (int reg = 0; reg < 16; reg++) {
                float v = acc[i][j][reg] + bv;
                int mg = mbase + (reg & 3) + 8 * (reg >> 2);
                if (EPI == 0) {
                    int which = n >> 10, c = n & 1023;
                    int h = c >> 6, d = c & 63;
                    int b = mg >> 11, t = mg & 2047;
                    u16* dst = (which == 0) ? (u16*)out0 : (which == 1 ? outK : outV);
                    dst[(((size_t)(b * NHEAD + h) * TT) + t) * HD + d] = f2bf(v);
                } else {
                    ((float*)out0)[(size_t)mg * NEMBD + n] = v;
                }
            }
        }
    }
}

// ---------------- transposed flash attention: one 128-row q-tile per block,
// fixed-base softmax, single-buffered K/V LDS + register prefetch.
// r12 structure (74.7) + r14 b64 Ps writes (73.8) -- session best, kept frozen.
// r13's K/V double-buffer (LDS 55296) cut capacity 4->2 blocks/CU and regressed
// (80.0); capacity IS binding -- cross-block wave overlap hides the barriers.
// Attn floor analysis (r14): MFMA busy ~14us = causal-triangle floor; VALU 53%
// dominated by exp2 chain (32/lane/step, quarter-rate) -- algorithmically
// irreducible.  BANK_CONFLICT 7.57M is hidden (b64 fusion halved write instrs,
// conflicts and dur ~unchanged).
// 1024 blocks, LDS 36864 B.  VGPR must stay <= 128: launch_bounds(256,2) --
// (256,4) squeezed arch-VGPRs to 64 and spilled ~110 MB scratch (r3, 2x regr).
// WORK BALANCE (r12, +11.7 us): work per block ~ (jq+1); co-resident blocks
// have blockIdx.y differing by 4k.  y -> jq via f = [b, 7-b, 15-b, 8+b][y>>2]
// (b = y&3): bijective; pairs (dy=8) sum to 17 work units, quadruples (dy=4)
// sum to 34 -- both co-residency granularities exactly balanced.
__global__ __launch_bounds__(256, 2)
void attn_kernel(const u16* __restrict__ Q, const u16* __restrict__ Kg,
                 const u16* __restrict__ V, u16* __restrict__ Y) {
    __shared__ u16 Ks[64][72];
    __shared__ u16 Vt[64][72];
    __shared__ u16 Ps[4][32][72];

    int tid = threadIdx.x;
    int lane = tid & 63, w = tid >> 6;
    int quad = lane >> 4, l16 = lane & 15;
    int bh = blockIdx.x;                 // 0..63
    int yb = blockIdx.y & 3, ya = blockIdx.y >> 2;
    int jq = (ya == 0) ? yb : (ya == 1) ? 7 - yb : (ya == 2) ? 15 - yb : 8 + yb;
    int q0 = jq * 128;
    const u16* Qb = Q  + (size_t)bh * TT * HD;
    const u16* Kb = Kg + (size_t)bh * TT * HD;
    const u16* Vb = V  + (size_t)bh * TT * HD;
    int wq = q0 + w * 32;

    const float C = 0.18033688f;  // (1/sqrt(64)) * log2(e), folded into Q

    short8 qf[2][2];
    for (int qt = 0; qt < 2; qt++)
        for (int kd = 0; kd < 2; kd++)
            qf[qt][kd] = scale8(*(const short8*)(Qb + (size_t)(wq + qt * 16 + l16) * HD + kd * 32 + quad * 8), C);

    floatx4 o[4][2];
    for (int dt = 0; dt < 4; dt++)
        for (int qt = 0; qt < 2; qt++)
            o[dt][qt] = (floatx4){0.f, 0.f, 0.f, 0.f};
    float l_s[2] = {0.f, 0.f};

    int krow = tid >> 2, kcg = (tid & 3) * 16;
    int vkp = (tid & 31) * 2, vd0 = (tid >> 5) * 8;

    auto stage_write = [&](uint4 k0v, uint4 k1v, uint4 v0, uint4 v1) {
        *(uint4*)&Ks[krow][kcg]     = k0v;
        *(uint4*)&Ks[krow][kcg + 8] = k1v;
        const unsigned* w0p = (const unsigned*)&v0;
        const unsigned* w1p = (const unsigned*)&v1;
        for (int e = 0; e < 4; e++) {
            *(unsigned*)&Vt[vd0 + 2 * e][vkp]     = __builtin_amdgcn_perm(w1p[e], w0p[e], 0x05040100u);
            *(unsigned*)&Vt[vd0 + 2 * e + 1][vkp] = __builtin_amdgcn_perm(w1p[e], w0p[e], 0x07060302u);
        }
    };

    auto process = [&](int k0) {
        short8 kf[4][2];
        for (int kt = 0; kt < 4; kt++)
            for (int kd = 0; kd < 2; kd++)
                kf[kt][kd] = *(const short8*)&Ks[kt * 16 + l16][kd * 32 + quad * 8];

        floatx4 s[2][4];
        for (int qt = 0; qt < 2; qt++)
            for (int kt = 0; kt < 4; kt++) {
                floatx4 a = (floatx4){0.f, 0.f, 0.f, 0.f};
                a = __builtin_amdgcn_mfma_f32_16x16x32_bf16(kf[kt][0], qf[qt][0], a, 0, 0, 0);
                a = __builtin_amdgcn_mfma_f32_16x16x32_bf16(kf[kt][1], qf[qt][1], a, 0, 0, 0);
                s[qt][kt] = a;
            }

        bool diag = (k0 + 64 > wq);
        for (int qt = 0; qt < 2; qt++) {
            int qg = wq + qt * 16 + l16;
            if (diag) {
                for (int kt = 0; kt < 4; kt++)
                    for (int r = 0; r < 4; r++)
                        if (k0 + kt * 16 + quad * 4 + r > qg) s[qt][kt][r] = -INFINITY;
            }
            float rs = 0.f;
            for (int kt = 0; kt < 4; kt++)
                for (int r = 0; r < 4; r++) {
                    float p = exp2f(s[qt][kt][r]);
                    s[qt][kt][r] = p;
                    rs += p;
                }
            l_s[qt] += rs;
        }

        for (int qt = 0; qt < 2; qt++)
            for (int kt = 0; kt < 4; kt++) {
                floatx4 p = s[qt][kt];
                uint2 pw;
                pw.x = trunc_pack(p[0], p[1]);
                pw.y = trunc_pack(p[2], p[3]);
                *(uint2*)&Ps[w][qt * 16 + l16][kt * 16 + quad * 4] = pw;
            }
        short8 pfrag[2][2];
        for (int qt = 0; qt < 2; qt++)
            for (int c = 0; c < 2; c++)
                pfrag[qt][c] = *(const short8*)&Ps[w][qt * 16 + l16][c * 32 + quad * 8];
        for (int c = 0; c < 2; c++)
            for (int dt = 0; dt < 4; dt++) {
                short8 vfrag = *(const short8*)&Vt[dt * 16 + l16][c * 32 + quad * 8];
                for (int qt = 0; qt < 2; qt++)
                    o[dt][qt] = __builtin_amdgcn_mfma_f32_16x16x32_bf16(vfrag, pfrag[qt][c], o[dt][qt], 0, 0, 0);
            }
    };

    // ---- prologue: stage step 0 ----
    {
        uint4 k0v = *(const uint4*)(Kb + (size_t)krow * HD + kcg);
        uint4 k1v = *(const uint4*)(Kb + (size_t)krow * HD + kcg + 8);
        uint4 v0  = *(const uint4*)(Vb + (size_t)vkp * HD + vd0);
        uint4 v1  = *(const uint4*)(Vb + (size_t)(vkp + 1) * HD + vd0);
        stage_write(k0v, k1v, v0, v1);
    }
    __syncthreads();

    int kend = q0 + 128;
    for (int k0 = 0; k0 < kend; k0 += 64) {
        bool pref = (k0 + 64 < kend);
        uint4 nk0, nk1, nv0, nv1;
        if (pref) {
            nk0 = *(const uint4*)(Kb + (size_t)(k0 + 64 + krow) * HD + kcg);
            nk1 = *(const uint4*)(Kb + (size_t)(k0 + 64 + krow) * HD + kcg + 8);
            nv0 = *(const uint4*)(Vb + (size_t)(k0 + 64 + vkp) * HD + vd0);
            nv1 = *(const uint4*)(Vb + (size_t)(k0 + 64 + vkp + 1) * HD + vd0);
        }

        if (k0 < wq + 32) process(k0);

        __syncthreads();
        if (pref) {
            stage_write(nk0, nk1, nv0, nv1);
        }
        __syncthreads();
    }

    // ---- epilogue: reduce l across quads, O^T[d][q] -> Y[b, q, h*64+d] ----
    int b = bh >> 4, h = bh & 15;
    for (int qt = 0; qt < 2; qt++) {
        float lt = l_s[qt];
        lt += __shfl_xor(lt, 16, 64);
        lt += __shfl_xor(lt, 32, 64);
        float inv = 1.0f / lt;
        int qg = wq + qt * 16 + l16;
        size_t base = ((size_t)(b * TT + qg)) * NEMBD + h * HD;
        for (int dt = 0; dt < 4; dt++) {
            *(unsigned*)&Y[base + dt * 16 + quad * 4]     = pack_bf16(o[dt][qt][0] * inv, o[dt][qt][1] * inv);
            *(unsigned*)&Y[base + dt * 16 + quad * 4 + 2] = pack_bf16(o[dt][qt][2] * inv, o[dt][qt][3] * inv);
        }
    }
}

extern "C" void kernel_launch(void* const* d_in, const int* in_sizes, int n_in,
                              void* d_out, int out_size, void* d_ws, size_t ws_size,
                              hipStream_t stream) {
    const float* x      = (const float*)d_in[0];
    const float* W_attn = (const float*)d_in[1];
    const float* b_attn = (const float*)d_in[2];
    const float* W_proj = (const float*)d_in[3];
    const float* b_proj = (const float*)d_in[4];
    float* out = (float*)d_out;

    char* ws = (char*)d_ws;
    u16* xb  = (u16*)(ws + 0);          // 16 MiB (reused as Y after QKV GEMM)
    u16* wat = (u16*)(ws + 16777216);   //  6 MiB
    u16* wpt = (u16*)(ws + 23068672);   //  2 MiB
    u16* Qb  = (u16*)(ws + 25165824);   // 16 MiB
    u16* Kb  = (u16*)(ws + 41943040);   // 16 MiB
    u16* Vb  = (u16*)(ws + 58720256);   // 16 MiB (end 75,497,472)

    prep_fused<<<12288, 256, 0, stream>>>(x, xb, W_attn, wat, W_proj, wpt);

    gemm_bt<0><<<dim3(NQKV / 128, MM / 128), 256, 0, stream>>>(xb, wat, b_attn, (void*)Qb, Kb, Vb);
    attn_kernel<<<dim3(BB * NHEAD, 16), 256, 0, stream>>>(Qb, Kb, Vb, xb);
    gemm_bt<1><<<dim3(NEMBD / 128, MM / 128), 256, 0, stream>>>(xb, wpt, b_proj, (void*)out, nullptr, nullptr);
}